// Round 7
// baseline (419.425 us; speedup 1.0000x reference)
//
#include <hip/hip_runtime.h>
#include <hip/hip_bf16.h>
#include <stdint.h>

#define H 12
#define S 2048
#define BATCH 2
#define DM 768
#define DH 64

typedef __attribute__((ext_vector_type(4))) float f32x4;
typedef __attribute__((ext_vector_type(4))) short s16x4;
typedef __attribute__((ext_vector_type(8))) short s16x8;

static __device__ __forceinline__ short f2bf(float f) {
  uint32_t u = __builtin_bit_cast(uint32_t, f);
  uint32_t r = (u + 0x7FFFu + ((u >> 16) & 1u)) >> 16;
  return (short)r;
}

static __device__ __forceinline__ s16x8 cvt8(f32x4 a, f32x4 b) {
  s16x8 r;
  r[0] = f2bf(a[0]); r[1] = f2bf(a[1]); r[2] = f2bf(a[2]); r[3] = f2bf(a[3]);
  r[4] = f2bf(b[0]); r[5] = f2bf(b[1]); r[6] = f2bf(b[2]); r[7] = f2bf(b[3]);
  return r;
}

static __device__ __forceinline__ f32x4 zero4() {
  f32x4 v; v[0] = 0.f; v[1] = 0.f; v[2] = 0.f; v[3] = 0.f; return v;
}

// bijective XCD-chunking swizzle (m204, n % 8 == 0)
static __device__ __forceinline__ int xcd_swz(int lin, int n) {
  int q = n >> 3;
  return (lin & 7) * q + (lin >> 3);
}

#define GLD_LDS16(g, l)                                                              \
  __builtin_amdgcn_global_load_lds((__attribute__((address_space(1))) const void*)(g), \
                                   (__attribute__((address_space(3))) void*)(l), 16, 0, 0)

#define WAITV(N) asm volatile("s_waitcnt vmcnt(" #N ")" ::: "memory")
#define WAITL0() asm volatile("s_waitcnt lgkmcnt(0)" ::: "memory")
#define BAR() __builtin_amdgcn_s_barrier()
#define FENCE() asm volatile("" ::: "memory")

// ---------------------------------------------------------------------------
// Kernel 0: weights -> bf16, transposed for b-fragment-contiguous reads.
// wt  : [3][H][64 n][768 k]  (W_{Q,K,V}^T per head)
// wot : [H][768 m][64 d]     (W_O^T per head)
// ---------------------------------------------------------------------------
__global__ __launch_bounds__(256) void k_prep(const float* __restrict__ wq,
                                              const float* __restrict__ wk,
                                              const float* __restrict__ wv,
                                              const float* __restrict__ wo,
                                              short* __restrict__ wt,
                                              short* __restrict__ wot) {
  int tid = blockIdx.x * 256 + threadIdx.x;
  int nthr = gridDim.x * 256;
  const int NQKV = 3 * H * DM * DH;
  for (int i = tid; i < NQKV; i += nthr) {
    int n = i & 63;
    int k = (i >> 6) % DM;
    int rest = (i >> 6) / DM;  // t*H + h
    int h = rest % H;
    int t = rest / H;
    const float* src = (t == 0 ? wq : t == 1 ? wk : wv);
    float v = src[((size_t)h * DM + k) * DH + n];
    wt[(((size_t)t * H + h) * DH + n) * DM + k] = f2bf(v);
  }
  const int NO = H * DH * DM;
  for (int i = tid; i < NO; i += nthr) {
    int m = i % DM;
    int d = (i / DM) % DH;
    int h = i / (DM * DH);
    wot[((size_t)h * DM + m) * DH + d] = f2bf(wo[((size_t)h * DH + d) * DM + m]);
  }
}

// ---------------------------------------------------------------------------
// Kernel 1: Q/K/V projection, slab-contiguous X streaming.
// grid = 768 blocks: (qchunk of 16 rows) x B x 3 tensors. Each block owns a
// CONTIGUOUS 16x(H*DM) X slab (576 KB) read exactly once, head-by-head.
// A_h (16x768 fp32, 48 KB) whole-staged via global_load_lds (pre-swizzled
// source), prefetched one head ahead; W_h in 8 KB chunks double-buffered.
// Uniform per-wave vmcnt(14) (12 A + 2 W in flight) + raw barriers,
// 144 identical iterations. Biases via LDS (no in-loop plain global loads).
// out: q_ws,k_ws = [b][h][s][64] bf16 ; vt_ws = [b][h][64 d][2048 kv] bf16
// ---------------------------------------------------------------------------
__global__ __launch_bounds__(256) void k_proj(
    const float* __restrict__ xq, const float* __restrict__ xk, const float* __restrict__ xv,
    const float* __restrict__ bq, const float* __restrict__ bk, const float* __restrict__ bv,
    const short* __restrict__ wt,
    short* __restrict__ q_ws, short* __restrict__ k_ws, short* __restrict__ vt_ws) {
  int work = xcd_swz(blockIdx.x, 768);
  const int t = work >> 8;          // 0..2
  const int b = (work >> 7) & 1;    // 0..1
  const int qc = work & 127;        // 0..127 (16-row chunk)

  const float* x = (t == 0 ? xq : t == 1 ? xk : xv);
  const float* xslab = x + (size_t)(b * S + qc * 16) * (H * DM);  // 16 rows x 9216 f32
  const short* wtt = wt + (size_t)t * H * DH * DM;                // + h*DH*DM

  __shared__ float A_sm[2][16 * 768];   // 2 x 48 KB, swizzled content
  __shared__ short W_sm[2][64 * 64];    // 2 x 8 KB, swizzled content
  __shared__ float bias_lds[H * DH];    // 3 KB

  const int tid = threadIdx.x;
  const int w = tid >> 6;
  const int l = tid & 63;
  const int g = l >> 4;
  const int m16 = l & 15;
  const int wswz = ((l & 7) ^ (l >> 3)) * 8;  // W source col offset (shorts)
  const int n2 = w * 16 + m16;                // this wave's n column

  // bias table -> LDS (plain loads settle before the pipeline starts)
  {
    const float* bp = (t == 0 ? bq : t == 1 ? bk : bv);
    for (int i = tid; i < H * DH; i += 256) bias_lds[i] = bp[i];
  }

// Stage A_h: 12 GLD insts/wave; inst j covers row w*4+j/3, 1KB seg j%3.
// Dest linear; source column pre-XOR-swizzled so reads can de-conflict.
#define STAGE_A(sel, hh)                                                             \
  do {                                                                               \
    _Pragma("unroll") for (int j = 0; j < 12; ++j) {                                 \
      int row = w * 4 + j / 3;                                                       \
      int seg = j % 3;                                                               \
      int srccol = ((seg * 1024 + l * 16) ^ ((row & 7) << 4)) >> 2;                  \
      GLD_LDS16(xslab + (size_t)row * (H * DM) + (size_t)(hh) * DM + srccol,         \
                (char*)A_sm + (sel) * 49152 + row * 3072 + seg * 1024);              \
    }                                                                                \
  } while (0)

// Stage W(h, kc): 2 GLD insts/wave (8 KB block-wide), swizzled source.
#define STAGE_W(sel, hh, kc)                                                         \
  do {                                                                               \
    _Pragma("unroll") for (int i = 0; i < 2; ++i) {                                  \
      int ch = w * 2 + i;                                                            \
      int n = ch * 8 + (l >> 3);                                                     \
      GLD_LDS16(wtt + (size_t)(hh) * (DH * DM) + (size_t)n * DM + (kc) * 64 + wswz,  \
                (char*)W_sm + (sel) * 8192 + ch * 1024);                             \
    }                                                                                \
  } while (0)

  STAGE_W(0, 0, 0);
  STAGE_A(0, 0);
  WAITL0(); BAR(); FENCE();

  short* dstqk_base = (t == 0 ? q_ws : k_ws) + (size_t)b * H * S * DH;
  f32x4 acc = zero4();

  for (int h = 0; h < 12; ++h) {
#pragma unroll
    for (int kc = 0; kc < 12; ++kc) {
      const int G = h * 12 + kc;
      if (kc == 0) {
        int hh = h + 1; if (hh > 11) hh = 11;    // clamped re-read, never consumed
        STAGE_A((h + 1) & 1, hh);
      }
      {
        int Gn = G + 1; if (Gn > 143) Gn = 143;  // clamped; sel stays (G+1)&1
        STAGE_W((G + 1) & 1, Gn / 12, Gn % 12);
      }
      WAITV(14);  // 12 A + 2 W stay in flight; chunk G (and A_h) landed
      BAR(); FENCE();
      if (kc == 0) acc = zero4();
      const char* Ab = (const char*)A_sm + (h & 1) * 49152;
      const char* Wb = (const char*)W_sm + (G & 1) * 8192;
      const int aswz = (m16 & 7) << 4;
#pragma unroll
      for (int qk = 0; qk < 2; ++qk) {
        int fb = (kc * 2 + qk) * 128 + g * 32;  // byte offset of a-frag in row
        f32x4 a0 = *(const f32x4*)(Ab + m16 * 3072 + (fb ^ aswz));
        f32x4 a1 = *(const f32x4*)(Ab + m16 * 3072 + ((fb + 16) ^ aswz));
        s16x8 afr = cvt8(a0, a1);
        s16x8 bfr = *(const s16x8*)(Wb + ((n2 * 128 + 16 * g + 64 * qk) ^ ((m16 & 7) << 4)));
        acc = __builtin_amdgcn_mfma_f32_16x16x32_bf16(afr, bfr, acc, 0, 0, 0);
      }
      if (kc == 11) {
        float bb = bias_lds[h * DH + n2];
        if (t < 2) {
          short* dst = dstqk_base + (size_t)h * S * DH;
#pragma unroll
          for (int r = 0; r < 4; ++r) {
            int q = qc * 16 + 4 * g + r;
            dst[(size_t)q * DH + n2] = f2bf(acc[r] + bb);
          }
        } else {
          short* dst = vt_ws + (size_t)(b * H + h) * DH * S;  // [d][kv]
          s16x4 pk;
          pk.x = f2bf(acc[0] + bb); pk.y = f2bf(acc[1] + bb);
          pk.z = f2bf(acc[2] + bb); pk.w = f2bf(acc[3] + bb);
          *(s16x4*)(dst + (size_t)n2 * S + qc * 16 + 4 * g) = pk;
        }
      }
      WAITL0(); BAR(); FENCE();
    }
  }
#undef STAGE_A
#undef STAGE_W
}

// ---------------------------------------------------------------------------
// Kernel 2: causal flash attention, counted-vmcnt double buffer. grid=(32,H,B)
// z_ws = [b][h][s][64] bf16
// ---------------------------------------------------------------------------
__global__ __launch_bounds__(256) void k_attn(const short* __restrict__ q_ws,
                                              const short* __restrict__ k_ws,
                                              const short* __restrict__ vt_ws,
                                              short* __restrict__ z_ws) {
  int lin = blockIdx.x + 32 * (blockIdx.y + 12 * blockIdx.z);
  lin = xcd_swz(lin, 32 * 12 * 2);
  const int q0 = (lin & 31) * 64;
  const int h = (lin >> 5) % 12;
  const int b = lin / (32 * 12);

  const size_t sl = (size_t)(b * H + h) * S * DH;
  const short* qs = q_ws + sl;
  const short* ks = k_ws + sl;
  const short* vs = vt_ws + sl;  // [64 d][2048 kv]
  short* zs = z_ws + sl;

  __shared__ short K_sm[2][64 * 64];
  __shared__ short V_sm[2][64 * 64];
  __shared__ short P_sm[4][16 * 72];

  const int tid = threadIdx.x;
  const int w = tid >> 6;
  const int l = tid & 63;
  const int g = l >> 4;
  const int m16 = l & 15;
  const int swz_src = ((l & 7) ^ (l >> 3)) * 8;

#define ATTN_STAGE(sel, kv0)                                                         \
  do {                                                                               \
    _Pragma("unroll") for (int i = 0; i < 2; ++i) {                                  \
      int ch = w * 2 + i;                                                            \
      int row = ch * 8 + (l >> 3);                                                   \
      GLD_LDS16(ks + (size_t)((kv0) + row) * DH + swz_src,                           \
                (char*)K_sm + (sel) * 8192 + ch * 1024);                             \
      GLD_LDS16(vs + (size_t)row * S + (kv0) + swz_src,                              \
                (char*)V_sm + (sel) * 8192 + ch * 1024);                             \
    }                                                                                \
  } while (0)

  s16x8 qf[2];
  {
    int q = q0 + 16 * w + m16;
    qf[0] = *(const s16x8*)(qs + (size_t)q * DH + 8 * g);
    qf[1] = *(const s16x8*)(qs + (size_t)q * DH + 8 * g + 32);
  }

  f32x4 o_acc[4];
  float m_run[4], l_run[4], alpha[4];
#pragma unroll
  for (int nt = 0; nt < 4; ++nt) o_acc[nt] = zero4();
#pragma unroll
  for (int r = 0; r < 4; ++r) { m_run[r] = -3.0e38f; l_run[r] = 0.f; }

  const int ktiles = (q0 >> 6) + 1;
  ATTN_STAGE(0, 0);  // 4 in flight
  for (int kt = 0; kt < ktiles; ++kt) {
    const int kv0 = kt * 64;
    const int cur = kt & 1;
    if (kt + 1 < ktiles) {
      ATTN_STAGE(cur ^ 1, kv0 + 64);
      WAITV(4);  // tile kt landed; tile kt+1 stays in flight
    } else {
      WAITV(0);
    }
    BAR(); FENCE();

    // S = Q K^T
    f32x4 sacc[4];
#pragma unroll
    for (int nt = 0; nt < 4; ++nt) sacc[nt] = zero4();
#pragma unroll
    for (int c = 0; c < 2; ++c) {
      int kr2 = (8 * g + 32 * c) * 2;
#pragma unroll
      for (int nt = 0; nt < 4; ++nt) {
        int row = m16 + 16 * nt;  // kv local
        s16x8 kf = *(const s16x8*)((const char*)K_sm + cur * 8192 +
                                   ((row * 128 + kr2) ^ ((row & 7) << 4)));
        sacc[nt] = __builtin_amdgcn_mfma_f32_16x16x32_bf16(qf[c], kf, sacc[nt], 0, 0, 0);
      }
    }
    // scale + causal mask
    float sv[4][4];
#pragma unroll
    for (int nt = 0; nt < 4; ++nt) {
      int kv = kv0 + 16 * nt + m16;
#pragma unroll
      for (int r = 0; r < 4; ++r) {
        int q = q0 + 16 * w + 4 * g + r;
        float s = sacc[nt][r] * 0.125f;
        sv[nt][r] = (kv > q) ? -1.0e30f : s;
      }
    }
    // online softmax
#pragma unroll
    for (int r = 0; r < 4; ++r) {
      float tm = fmaxf(fmaxf(sv[0][r], sv[1][r]), fmaxf(sv[2][r], sv[3][r]));
      tm = fmaxf(tm, __shfl_xor(tm, 1));
      tm = fmaxf(tm, __shfl_xor(tm, 2));
      tm = fmaxf(tm, __shfl_xor(tm, 4));
      tm = fmaxf(tm, __shfl_xor(tm, 8));
      float mn = fmaxf(m_run[r], tm);
      alpha[r] = __expf(m_run[r] - mn);
      m_run[r] = mn;
      float rs = 0.f;
#pragma unroll
      for (int nt = 0; nt < 4; ++nt) {
        float p = __expf(sv[nt][r] - mn);
        sv[nt][r] = p;
        rs += p;
      }
      rs += __shfl_xor(rs, 1);
      rs += __shfl_xor(rs, 2);
      rs += __shfl_xor(rs, 4);
      rs += __shfl_xor(rs, 8);
      l_run[r] = l_run[r] * alpha[r] + rs;
    }
    // P -> bf16 -> per-wave LDS bounce
#pragma unroll
    for (int nt = 0; nt < 4; ++nt)
#pragma unroll
      for (int r = 0; r < 4; ++r)
        P_sm[w][(4 * g + r) * 72 + 16 * nt + m16] = f2bf(sv[nt][r]);
    // rescale O
#pragma unroll
    for (int nt = 0; nt < 4; ++nt)
#pragma unroll
      for (int r = 0; r < 4; ++r) o_acc[nt][r] *= alpha[r];
    // O += P V
#pragma unroll
    for (int c = 0; c < 2; ++c) {
      s16x8 pf = *(const s16x8*)(&P_sm[w][m16 * 72 + 8 * g + 32 * c]);
      int kv2 = (8 * g + 32 * c) * 2;
#pragma unroll
      for (int nt = 0; nt < 4; ++nt) {
        int d = m16 + 16 * nt;
        s16x8 vf = *(const s16x8*)((const char*)V_sm + cur * 8192 +
                                   ((d * 128 + kv2) ^ ((d & 7) << 4)));
        o_acc[nt] = __builtin_amdgcn_mfma_f32_16x16x32_bf16(pf, vf, o_acc[nt], 0, 0, 0);
      }
    }
    WAITL0(); BAR(); FENCE();
  }
#pragma unroll
  for (int nt = 0; nt < 4; ++nt) {
    int d = 16 * nt + m16;
#pragma unroll
    for (int r = 0; r < 4; ++r) {
      int q = q0 + 16 * w + 4 * g + r;
      zs[(size_t)q * DH + d] = f2bf(o_acc[nt][r] / l_run[r]);
    }
  }
}

// ---------------------------------------------------------------------------
// Kernel 3: output projection + bias, counted-vmcnt double buffer. grid=(32,H,B)
// out[b][q][h][m] = sum_d z[b][h][q][d] * W_O[h][d][m] + b_O[m]/H
// ---------------------------------------------------------------------------
__global__ __launch_bounds__(256) void k_oproj(const short* __restrict__ z_ws,
                                               const short* __restrict__ wot,
                                               const float* __restrict__ bo,
                                               float* __restrict__ out) {
  int lin = blockIdx.x + 32 * (blockIdx.y + 12 * blockIdx.z);
  lin = xcd_swz(lin, 32 * 12 * 2);
  const int q0 = (lin & 31) * 64;
  const int h = (lin >> 5) % 12;
  const int b = lin / (32 * 12);

  const short* zs = z_ws + (size_t)(b * H + h) * S * DH;
  const short* wos = wot + (size_t)h * DM * DH;  // [768 m][64 d]

  __shared__ short Z_sm[64 * 64];
  __shared__ short W_sm[2][128 * 64];

  const int tid = threadIdx.x;
  const int w = tid >> 6;
  const int l = tid & 63;
  const int g = l >> 4;
  const int m16 = l & 15;
  const int swz_src = ((l & 7) ^ (l >> 3)) * 8;

#define OPROJ_STAGE_W(sel, n0)                                                       \
  do {                                                                               \
    _Pragma("unroll") for (int i = 0; i < 4; ++i) {                                  \
      int ch = w * 4 + i;                                                            \
      int row = ch * 8 + (l >> 3);                                                   \
      GLD_LDS16(wos + (size_t)((n0) + row) * DH + swz_src,                           \
                (char*)W_sm + (sel) * 16384 + ch * 1024);                            \
    }                                                                                \
  } while (0)

#pragma unroll
  for (int i = 0; i < 2; ++i) {
    int ch = w * 2 + i;
    int row = ch * 8 + (l >> 3);
    GLD_LDS16(zs + (size_t)(q0 + row) * DH + swz_src, (char*)Z_sm + ch * 1024);
  }
  OPROJ_STAGE_W(0, 0);
  WAITV(4);  // Z landed; W0 may still fly
  BAR(); FENCE();

  s16x8 af[2];
#pragma unroll
  for (int c = 0; c < 2; ++c) {
    int row = 16 * w + m16;
    int kr2 = (8 * g + 32 * c) * 2;
    af[c] = *(const s16x8*)((const char*)Z_sm + ((row * 128 + kr2) ^ ((row & 7) << 4)));
  }

#pragma unroll
  for (int nc = 0; nc < 6; ++nc) {
    const int n0 = nc * 128;
    const int cur = nc & 1;
    if (nc < 5) {
      OPROJ_STAGE_W(cur ^ 1, n0 + 128);
      WAITV(4);  // chunk nc landed; chunk nc+1 stays in flight
    } else {
      WAITV(0);
    }
    BAR(); FENCE();
    f32x4 acc[8];
#pragma unroll
    for (int nt = 0; nt < 8; ++nt) acc[nt] = zero4();
#pragma unroll
    for (int c = 0; c < 2; ++c) {
      int kr2 = (8 * g + 32 * c) * 2;
#pragma unroll
      for (int nt = 0; nt < 8; ++nt) {
        int row = m16 + 16 * nt;  // m local
        s16x8 bf = *(const s16x8*)((const char*)W_sm + cur * 16384 +
                                   ((row * 128 + kr2) ^ ((row & 7) << 4)));
        acc[nt] = __builtin_amdgcn_mfma_f32_16x16x32_bf16(af[c], bf, acc[nt], 0, 0, 0);
      }
    }
#pragma unroll
    for (int nt = 0; nt < 8; ++nt) {
      int m = n0 + 16 * nt + m16;
      float bias = bo[m] * (1.0f / 12.0f);
#pragma unroll
      for (int r = 0; r < 4; ++r) {
        int q = q0 + 16 * w + 4 * g + r;
        out[((size_t)(b * S + q) * H + h) * DM + m] = acc[nt][r] + bias;
      }
    }
    WAITL0(); BAR(); FENCE();
  }
}

// ---------------------------------------------------------------------------
extern "C" void kernel_launch(void* const* d_in, const int* in_sizes, int n_in,
                              void* d_out, int out_size, void* d_ws, size_t ws_size,
                              hipStream_t stream) {
  const float* xq = (const float*)d_in[0];
  const float* xk = (const float*)d_in[1];
  const float* xv = (const float*)d_in[2];
  const float* wq = (const float*)d_in[3];
  const float* bq = (const float*)d_in[4];
  const float* wk = (const float*)d_in[5];
  const float* bk = (const float*)d_in[6];
  const float* wv = (const float*)d_in[7];
  const float* bv = (const float*)d_in[8];
  const float* wo = (const float*)d_in[9];
  const float* bo = (const float*)d_in[10];
  float* out = (float*)d_out;

  short* wt = (short*)d_ws;                                   // 3*H*64*768
  short* wot = wt + (size_t)3 * H * DH * DM;                  // H*768*64
  short* q_ws = wot + (size_t)H * DM * DH;
  short* k_ws = q_ws + (size_t)BATCH * H * S * DH;
  short* vt_ws = k_ws + (size_t)BATCH * H * S * DH;
  short* z_ws = vt_ws + (size_t)BATCH * H * S * DH;

  k_prep<<<dim3(1024), dim3(256), 0, stream>>>(wq, wk, wv, wo, wt, wot);
  k_proj<<<dim3(768), dim3(256), 0, stream>>>(xq, xk, xv, bq, bk, bv, wt, q_ws, k_ws, vt_ws);
  k_attn<<<dim3(32, H, BATCH), dim3(256), 0, stream>>>(q_ws, k_ws, vt_ws, z_ws);
  k_oproj<<<dim3(32, H, BATCH), dim3(256), 0, stream>>>(z_ws, wot, bo, out);
}

// Round 8
// 218.972 us; speedup vs baseline: 1.9154x; 1.9154x over previous
//
#include <hip/hip_runtime.h>
#include <hip/hip_bf16.h>
#include <stdint.h>

#define H 12
#define S 2048
#define BATCH 2
#define DM 768
#define DH 64

typedef __attribute__((ext_vector_type(4))) float f32x4;
typedef __attribute__((ext_vector_type(4))) short s16x4;
typedef __attribute__((ext_vector_type(8))) short s16x8;

static __device__ __forceinline__ short f2bf(float f) {
  uint32_t u = __builtin_bit_cast(uint32_t, f);
  uint32_t r = (u + 0x7FFFu + ((u >> 16) & 1u)) >> 16;
  return (short)r;
}

static __device__ __forceinline__ s16x8 cvt8(f32x4 a, f32x4 b) {
  s16x8 r;
  r[0] = f2bf(a[0]); r[1] = f2bf(a[1]); r[2] = f2bf(a[2]); r[3] = f2bf(a[3]);
  r[4] = f2bf(b[0]); r[5] = f2bf(b[1]); r[6] = f2bf(b[2]); r[7] = f2bf(b[3]);
  return r;
}

static __device__ __forceinline__ f32x4 zero4() {
  f32x4 v; v[0] = 0.f; v[1] = 0.f; v[2] = 0.f; v[3] = 0.f; return v;
}

#define GLD_LDS16(g, l)                                                              \
  __builtin_amdgcn_global_load_lds((__attribute__((address_space(1))) const void*)(g), \
                                   (__attribute__((address_space(3))) void*)(l), 16, 0, 0)

#define WAITV(N) asm volatile("s_waitcnt vmcnt(" #N ")" ::: "memory")
#define WAITL0() asm volatile("s_waitcnt lgkmcnt(0)" ::: "memory")
#define BAR() __builtin_amdgcn_s_barrier()
#define FENCE() asm volatile("" ::: "memory")

// ---------------------------------------------------------------------------
// Kernel 0: weights -> bf16, transposed.
// wt  : [3][H][64 n][768 k]  (W_{Q,K,V}^T per head)
// wot : [H][768 m][64 d]     (W_O^T per head)
// ---------------------------------------------------------------------------
__global__ __launch_bounds__(256) void k_prep(const float* __restrict__ wq,
                                              const float* __restrict__ wk,
                                              const float* __restrict__ wv,
                                              const float* __restrict__ wo,
                                              short* __restrict__ wt,
                                              short* __restrict__ wot) {
  int tid = blockIdx.x * 256 + threadIdx.x;
  int nthr = gridDim.x * 256;
  const int NQKV = 3 * H * DM * DH;
  for (int i = tid; i < NQKV; i += nthr) {
    int n = i & 63;
    int k = (i >> 6) % DM;
    int rest = (i >> 6) / DM;  // t*H + h
    int h = rest % H;
    int t = rest / H;
    const float* src = (t == 0 ? wq : t == 1 ? wk : wv);
    float v = src[((size_t)h * DM + k) * DH + n];
    wt[(((size_t)t * H + h) * DH + n) * DM + k] = f2bf(v);
  }
  const int NO = H * DH * DM;
  for (int i = tid; i < NO; i += nthr) {
    int m = i % DM;
    int d = (i / DM) % DH;
    int h = i / (DM * DH);
    wot[((size_t)h * DM + m) * DH + d] = f2bf(wo[((size_t)h * DH + d) * DM + m]);
  }
}

// ---------------------------------------------------------------------------
// Kernel 1: Q/K/V projection — R5 body, REGION-CO-SCHEDULED mapping.
// u -> (xcd = u&7, slot = u>>3); region r = (slot/12)*8 + xcd; h = slot%12.
// The 12 h-blocks of one (t,b,qtile) region occupy consecutive slots on one
// XCD => co-resident => their 2.3 MB X span is HBM-fetched once, re-served
// from L2/L3; HBM sees ~8 interleaved sequential streams, not 50K pokes.
// ---------------------------------------------------------------------------
__global__ __launch_bounds__(256) void k_proj(
    const float* __restrict__ xq, const float* __restrict__ xk, const float* __restrict__ xv,
    const float* __restrict__ bq, const float* __restrict__ bk, const float* __restrict__ bv,
    const short* __restrict__ wt,
    short* __restrict__ q_ws, short* __restrict__ k_ws, short* __restrict__ vt_ws) {
  const int u = blockIdx.x;          // 0..2303
  const int xcd = u & 7;
  const int slot = u >> 3;           // 0..287
  const int r = (slot / 12) * 8 + xcd;  // 0..191 region (t,b,qtile)
  const int h = slot % 12;
  const int t = r / 64;
  const int rb = r % 64;
  const int b = rb >> 5;
  const int q0 = (rb & 31) * 64;

  const float* x = (t == 0 ? xq : t == 1 ? xk : xv);
  const float* xbase = x + ((size_t)(b * S + q0) * H + h) * DM;     // row stride H*DM
  const short* wbase = wt + ((size_t)t * H + h) * (size_t)DH * DM;  // [64 n][768 k]

  __shared__ float A_sm[2][64 * 64];  // 16 KB/half, swizzled content
  __shared__ short W_sm[2][64 * 64];  // 8 KB/half, swizzled content

  const int tid = threadIdx.x;
  const int w = tid >> 6;
  const int l = tid & 63;
  const int g = l >> 4;
  const int m16 = l & 15;
  const int wswz = ((l & 7) ^ (l >> 3)) * 8;  // W source col (shorts)

  const int arow_st = (l >> 4);
  const int apb = (l & 15) * 16;

  f32x4 acc[4];
#pragma unroll
  for (int nt = 0; nt < 4; ++nt) acc[nt] = zero4();

#define PROJ_STAGE(sel, kc)                                                          \
  do {                                                                               \
    _Pragma("unroll") for (int i = 0; i < 4; ++i) {                                  \
      int row = (w * 4 + i) * 4 + arow_st;                                           \
      int colf = (apb ^ ((row & 7) << 4)) >> 2;                                      \
      GLD_LDS16(xbase + (size_t)row * (H * DM) + (kc) * 64 + colf,                   \
                (char*)A_sm + (sel) * 16384 + (w * 4 + i) * 1024);                   \
    }                                                                                \
    _Pragma("unroll") for (int i = 0; i < 2; ++i) {                                  \
      int ch = w * 2 + i;                                                            \
      int n = ch * 8 + (l >> 3);                                                     \
      GLD_LDS16(wbase + (size_t)n * DM + (kc) * 64 + wswz,                           \
                (char*)W_sm + (sel) * 8192 + ch * 1024);                             \
    }                                                                                \
  } while (0)

#define PROJ_COMPUTE(sel)                                                            \
  do {                                                                               \
    const char* Ab = (const char*)A_sm + (sel) * 16384;                              \
    const char* Wb = (const char*)W_sm + (sel) * 8192;                               \
    int arow = 16 * w + m16;                                                         \
    int asw = (arow & 7) << 4;                                                       \
    _Pragma("unroll") for (int c = 0; c < 2; ++c) {                                  \
      f32x4 a0 = *(const f32x4*)(Ab + arow * 256 + ((32 * g + 128 * c) ^ asw));      \
      f32x4 a1 = *(const f32x4*)(Ab + arow * 256 + ((32 * g + 128 * c + 16) ^ asw)); \
      s16x8 afr = cvt8(a0, a1);                                                      \
      int krow = 8 * g + 32 * c;                                                     \
      _Pragma("unroll") for (int nt = 0; nt < 4; ++nt) {                             \
        int n = m16 + 16 * nt;                                                       \
        s16x8 bfr = *(const s16x8*)(Wb + ((n * 128 + krow * 2) ^ ((n & 7) << 4)));   \
        acc[nt] = __builtin_amdgcn_mfma_f32_16x16x32_bf16(afr, bfr, acc[nt], 0, 0, 0); \
      }                                                                              \
    }                                                                                \
  } while (0)

  PROJ_STAGE(0, 0);  // 6 vmem in flight
#pragma unroll
  for (int kc = 0; kc < 12; ++kc) {
    const int cur = kc & 1;
    if (kc < 11) {
      PROJ_STAGE(cur ^ 1, kc + 1);
      WAITV(6);  // chunk kc landed; chunk kc+1 stays in flight
    } else {
      WAITV(0);
    }
    BAR(); FENCE();
    PROJ_COMPUTE(cur);
    WAITL0(); BAR(); FENCE();
  }

  const float* bias = (t == 0 ? bq : t == 1 ? bk : bv) + h * DH;
  if (t < 2) {
    short* dst = (t == 0 ? q_ws : k_ws) + (size_t)(b * H + h) * S * DH;
#pragma unroll
    for (int nt = 0; nt < 4; ++nt) {
      int n = 16 * nt + m16;
      float bb = bias[n];
#pragma unroll
      for (int r2 = 0; r2 < 4; ++r2) {
        int q = q0 + 16 * w + 4 * g + r2;
        dst[(size_t)q * DH + n] = f2bf(acc[nt][r2] + bb);
      }
    }
  } else {
    short* dst = vt_ws + (size_t)(b * H + h) * DH * S;  // [d][kv]
#pragma unroll
    for (int nt = 0; nt < 4; ++nt) {
      int n = 16 * nt + m16;  // d
      float bb = bias[n];
#pragma unroll
      for (int r2 = 0; r2 < 4; ++r2) {
        int q = q0 + 16 * w + 4 * g + r2;  // kv
        dst[(size_t)n * S + q] = f2bf(acc[nt][r2] + bb);
      }
    }
  }
}

// ---------------------------------------------------------------------------
// Kernel 2: causal flash attention FUSED with output projection.
// grid = 768; region mapping like k_proj (12 h-blocks of one (b,qtile)
// co-resident on one XCD); heavy qtiles dispatched first.
// Epilogue: z (registers) -> Z_sm (reuses K_sm), W_O chunks double-buffered
// in V_sm space, out written directly. b_O via LDS (reuses P_sm).
// ---------------------------------------------------------------------------
__global__ __launch_bounds__(256) void k_attn_o(const short* __restrict__ q_ws,
                                                const short* __restrict__ k_ws,
                                                const short* __restrict__ vt_ws,
                                                const short* __restrict__ wot,
                                                const float* __restrict__ bo,
                                                float* __restrict__ out) {
  const int u = blockIdx.x;         // 0..767
  const int xcd = u & 7;
  const int slot = u >> 3;          // 0..95
  const int r = (slot / 12) * 8 + xcd;  // 0..63 region (b,qtile)
  const int h = slot % 12;
  const int b = r >> 5;
  const int qtile = 31 - (r & 31);  // heavy (late) q-tiles first
  const int q0 = qtile * 64;

  const size_t sl = (size_t)(b * H + h) * S * DH;
  const short* qs = q_ws + sl;
  const short* ks = k_ws + sl;
  const short* vs = vt_ws + sl;  // [64 d][2048 kv]

  __shared__ short K_sm[2][64 * 64];
  __shared__ short V_sm[2][64 * 64];
  __shared__ short P_sm[4][16 * 72];

  const int tid = threadIdx.x;
  const int w = tid >> 6;
  const int l = tid & 63;
  const int g = l >> 4;
  const int m16 = l & 15;
  const int swz_src = ((l & 7) ^ (l >> 3)) * 8;

#define ATTN_STAGE(sel, kv0)                                                         \
  do {                                                                               \
    _Pragma("unroll") for (int i = 0; i < 2; ++i) {                                  \
      int ch = w * 2 + i;                                                            \
      int row = ch * 8 + (l >> 3);                                                   \
      GLD_LDS16(ks + (size_t)((kv0) + row) * DH + swz_src,                           \
                (char*)K_sm + (sel) * 8192 + ch * 1024);                             \
      GLD_LDS16(vs + (size_t)row * S + (kv0) + swz_src,                              \
                (char*)V_sm + (sel) * 8192 + ch * 1024);                             \
    }                                                                                \
  } while (0)

  s16x8 qf[2];
  {
    int q = q0 + 16 * w + m16;
    qf[0] = *(const s16x8*)(qs + (size_t)q * DH + 8 * g);
    qf[1] = *(const s16x8*)(qs + (size_t)q * DH + 8 * g + 32);
  }

  f32x4 o_acc[4];
  float m_run[4], l_run[4], alpha[4];
#pragma unroll
  for (int nt = 0; nt < 4; ++nt) o_acc[nt] = zero4();
#pragma unroll
  for (int rr = 0; rr < 4; ++rr) { m_run[rr] = -3.0e38f; l_run[rr] = 0.f; }

  const int ktiles = qtile + 1;
  ATTN_STAGE(0, 0);  // 4 in flight
  for (int kt = 0; kt < ktiles; ++kt) {
    const int kv0 = kt * 64;
    const int cur = kt & 1;
    if (kt + 1 < ktiles) {
      ATTN_STAGE(cur ^ 1, kv0 + 64);
      WAITV(4);
    } else {
      WAITV(0);
    }
    BAR(); FENCE();

    // S = Q K^T
    f32x4 sacc[4];
#pragma unroll
    for (int nt = 0; nt < 4; ++nt) sacc[nt] = zero4();
#pragma unroll
    for (int c = 0; c < 2; ++c) {
      int kr2 = (8 * g + 32 * c) * 2;
#pragma unroll
      for (int nt = 0; nt < 4; ++nt) {
        int row = m16 + 16 * nt;  // kv local
        s16x8 kf = *(const s16x8*)((const char*)K_sm + cur * 8192 +
                                   ((row * 128 + kr2) ^ ((row & 7) << 4)));
        sacc[nt] = __builtin_amdgcn_mfma_f32_16x16x32_bf16(qf[c], kf, sacc[nt], 0, 0, 0);
      }
    }
    // scale + causal mask
    float sv[4][4];
#pragma unroll
    for (int nt = 0; nt < 4; ++nt) {
      int kv = kv0 + 16 * nt + m16;
#pragma unroll
      for (int rr = 0; rr < 4; ++rr) {
        int q = q0 + 16 * w + 4 * g + rr;
        float s = sacc[nt][rr] * 0.125f;
        sv[nt][rr] = (kv > q) ? -1.0e30f : s;
      }
    }
    // online softmax
#pragma unroll
    for (int rr = 0; rr < 4; ++rr) {
      float tm = fmaxf(fmaxf(sv[0][rr], sv[1][rr]), fmaxf(sv[2][rr], sv[3][rr]));
      tm = fmaxf(tm, __shfl_xor(tm, 1));
      tm = fmaxf(tm, __shfl_xor(tm, 2));
      tm = fmaxf(tm, __shfl_xor(tm, 4));
      tm = fmaxf(tm, __shfl_xor(tm, 8));
      float mn = fmaxf(m_run[rr], tm);
      alpha[rr] = __expf(m_run[rr] - mn);
      m_run[rr] = mn;
      float rs = 0.f;
#pragma unroll
      for (int nt = 0; nt < 4; ++nt) {
        float p = __expf(sv[nt][rr] - mn);
        sv[nt][rr] = p;
        rs += p;
      }
      rs += __shfl_xor(rs, 1);
      rs += __shfl_xor(rs, 2);
      rs += __shfl_xor(rs, 4);
      rs += __shfl_xor(rs, 8);
      l_run[rr] = l_run[rr] * alpha[rr] + rs;
    }
    // P -> bf16 -> per-wave LDS bounce
#pragma unroll
    for (int nt = 0; nt < 4; ++nt)
#pragma unroll
      for (int rr = 0; rr < 4; ++rr)
        P_sm[w][(4 * g + rr) * 72 + 16 * nt + m16] = f2bf(sv[nt][rr]);
    // rescale O
#pragma unroll
    for (int nt = 0; nt < 4; ++nt)
#pragma unroll
      for (int rr = 0; rr < 4; ++rr) o_acc[nt][rr] *= alpha[rr];
    // O += P V
#pragma unroll
    for (int c = 0; c < 2; ++c) {
      s16x8 pf = *(const s16x8*)(&P_sm[w][m16 * 72 + 8 * g + 32 * c]);
      int kv2 = (8 * g + 32 * c) * 2;
#pragma unroll
      for (int nt = 0; nt < 4; ++nt) {
        int d = m16 + 16 * nt;
        s16x8 vf = *(const s16x8*)((const char*)V_sm + cur * 8192 +
                                   ((d * 128 + kv2) ^ ((d & 7) << 4)));
        o_acc[nt] = __builtin_amdgcn_mfma_f32_16x16x32_bf16(pf, vf, o_acc[nt], 0, 0, 0);
      }
    }
    WAITL0(); BAR(); FENCE();
  }

  // ================= fused output projection =================
  // LDS reuse: Z_sm = K_sm (8 KB), WO_sm = V_sm (2x8 KB), bo_lds = P_sm (3 KB)
  short* Z_sm = (short*)K_sm;
  char* WO_sm = (char*)V_sm;
  float* bo_lds = (float*)P_sm;
  const short* wos = wot + (size_t)h * DM * DH;  // [768 m][64 d]

#define STAGE_WO(sel, nc)                                                            \
  do {                                                                               \
    _Pragma("unroll") for (int i = 0; i < 2; ++i) {                                  \
      int ch = w * 2 + i;                                                            \
      int row = ch * 8 + (l >> 3);                                                   \
      GLD_LDS16(wos + (size_t)((nc) * 64 + row) * DH + swz_src,                      \
                WO_sm + (sel) * 8192 + ch * 1024);                                   \
    }                                                                                \
  } while (0)

  STAGE_WO(0, 0);  // hide under Z/bias staging
  // bias table (b_O/H) -> LDS
  for (int i = tid; i < DM; i += 256) bo_lds[i] = bo[i] * (1.0f / 12.0f);
  // z -> Z_sm (swizzled), z = o/l
#pragma unroll
  for (int nt = 0; nt < 4; ++nt) {
#pragma unroll
    for (int rr = 0; rr < 4; ++rr) {
      int row = 16 * w + 4 * g + rr;              // q local
      int d = 16 * nt + m16;
      int byte = (row * 128 + d * 2) ^ ((row & 7) << 4);
      *(short*)((char*)Z_sm + byte) = f2bf(o_acc[nt][rr] / l_run[rr]);
    }
  }
  WAITL0(); BAR(); FENCE();

  s16x8 af[2];
#pragma unroll
  for (int c = 0; c < 2; ++c) {
    int row = 16 * w + m16;
    int kr2 = (8 * g + 32 * c) * 2;
    af[c] = *(const s16x8*)((const char*)Z_sm + ((row * 128 + kr2) ^ ((row & 7) << 4)));
  }

#pragma unroll
  for (int nc = 0; nc < 12; ++nc) {
    const int cur = nc & 1;
    if (nc < 11) {
      STAGE_WO(cur ^ 1, nc + 1);
      if (nc == 0) { WAITV(2); }   // only glds outstanding
      else        { WAITV(18); }   // 16 stores(prev) + 2 glds newest; older glds drained
    } else {
      WAITV(0);
    }
    BAR(); FENCE();
    f32x4 acc[4];
#pragma unroll
    for (int nt = 0; nt < 4; ++nt) acc[nt] = zero4();
#pragma unroll
    for (int c = 0; c < 2; ++c) {
      int kr2 = (8 * g + 32 * c) * 2;
#pragma unroll
      for (int nt = 0; nt < 4; ++nt) {
        int row = m16 + 16 * nt;  // m local
        s16x8 bf = *(const s16x8*)(WO_sm + cur * 8192 +
                                   ((row * 128 + kr2) ^ ((row & 7) << 4)));
        acc[nt] = __builtin_amdgcn_mfma_f32_16x16x32_bf16(af[c], bf, acc[nt], 0, 0, 0);
      }
    }
#pragma unroll
    for (int nt = 0; nt < 4; ++nt) {
      int m = nc * 64 + 16 * nt + m16;
      float bias = bo_lds[m];
#pragma unroll
      for (int rr = 0; rr < 4; ++rr) {
        int q = q0 + 16 * w + 4 * g + rr;
        out[((size_t)(b * S + q) * H + h) * DM + m] = acc[nt][rr] + bias;
      }
    }
    WAITL0(); BAR(); FENCE();
  }
#undef STAGE_WO
#undef ATTN_STAGE
}

// ---------------------------------------------------------------------------
extern "C" void kernel_launch(void* const* d_in, const int* in_sizes, int n_in,
                              void* d_out, int out_size, void* d_ws, size_t ws_size,
                              hipStream_t stream) {
  const float* xq = (const float*)d_in[0];
  const float* xk = (const float*)d_in[1];
  const float* xv = (const float*)d_in[2];
  const float* wq = (const float*)d_in[3];
  const float* bq = (const float*)d_in[4];
  const float* wk = (const float*)d_in[5];
  const float* bk = (const float*)d_in[6];
  const float* wv = (const float*)d_in[7];
  const float* bv = (const float*)d_in[8];
  const float* wo = (const float*)d_in[9];
  const float* bo = (const float*)d_in[10];
  float* out = (float*)d_out;

  short* wt = (short*)d_ws;                                   // 3*H*64*768
  short* wot = wt + (size_t)3 * H * DH * DM;                  // H*768*64
  short* q_ws = wot + (size_t)H * DM * DH;
  short* k_ws = q_ws + (size_t)BATCH * H * S * DH;
  short* vt_ws = k_ws + (size_t)BATCH * H * S * DH;

  k_prep<<<dim3(1024), dim3(256), 0, stream>>>(wq, wk, wv, wo, wt, wot);
  k_proj<<<dim3(2304), dim3(256), 0, stream>>>(xq, xk, xv, bq, bk, bv, wt, q_ws, k_ws, vt_ws);
  k_attn_o<<<dim3(768), dim3(256), 0, stream>>>(q_ws, k_ws, vt_ws, wot, bo, out);
}